// Round 4
// baseline (312.653 us; speedup 1.0000x reference)
//
#include <hip/hip_runtime.h>
#include <stdint.h>

#define Bdim 16
#define Sdim 4096
#define Hdim 512
#define Mdim (Bdim*Sdim)      // 65536
#define N3   (3*Hdim)         // 1536
#define Kdim 512
#define NCHUNK 64
#define CLEN  (Sdim/NCHUNK)   // 64

typedef __bf16 bf16;
typedef __bf16 bf16x4 __attribute__((ext_vector_type(4)));
typedef __bf16 bf16x8 __attribute__((ext_vector_type(8)));
typedef float  f32x4  __attribute__((ext_vector_type(4)));
typedef _Float16 f16;
typedef _Float16 f16x4 __attribute__((ext_vector_type(4)));
typedef _Float16 f16x8 __attribute__((ext_vector_type(8)));

__device__ __forceinline__ void gload_lds16(const void* g, void* l) {
  __builtin_amdgcn_global_load_lds(
      (const __attribute__((address_space(1))) uint32_t*)g,
      (__attribute__((address_space(3))) uint32_t*)l, 16, 0, 0);
}

// ---------- fp32 -> bf16 convert (vectorized) ----------
__global__ void __launch_bounds__(256) cvt_kernel(const float4* __restrict__ in,
                                                  bf16x4* __restrict__ out, int n4) {
  int i = blockIdx.x * blockDim.x + threadIdx.x;
  if (i >= n4) return;
  float4 v = in[i];
  bf16x4 o;
  o.x = (bf16)v.x; o.y = (bf16)v.y; o.z = (bf16)v.z; o.w = (bf16)v.w;
  out[i] = o;
}

// ---------- bf16 MFMA GEMM, 256x256 tile, counted-vmcnt ring pipeline ----------
// A: (M,K) bf16 row-major; Wb: (N,K) bf16 row-major. C = A*Wb^T.
// BK=32 per K-step, 4-slot LDS ring (4 x 32KB), prefetch distance 3,
// s_waitcnt vmcnt(8) + raw s_barrier per iter (loads stay in flight across
// barriers). XOR swizzle kslot^((row>>1)&3) on both stage-source and ds_read.
#define BM 256
#define BN 256
#define BK2 32
#define NT (Kdim/BK2)   // 16

__global__ void __launch_bounds__(512, 2) gemm_act_kernel(
    const bf16* __restrict__ A, const bf16* __restrict__ Wb,
    const float* __restrict__ bias,
    f16* __restrict__ zbuf, f16* __restrict__ fbuf, f16* __restrict__ ogbuf) {
  __shared__ char lds[131072];  // ring slot r at r*32768: A 16KB then B 16KB
  const int tid  = threadIdx.x;
  const int wid  = tid >> 6;
  const int lane = tid & 63;
  const int wr = wid >> 2, wc = wid & 3;   // 2(M) x 4(N) wave grid; wave tile 128x64
  // XCD-chunked bijective swizzle: 1536 blocks = 8 XCDs x 192
  const int bid = blockIdx.x;
  const int wg  = (bid & 7) * 192 + (bid >> 3);
  const int mt = wg / (N3 / BN);
  const int nt = wg % (N3 / BN);           // 6 N-tiles, inner -> A reuse per XCD
  const int row0 = mt * BM;

  const bf16* Ag = A  + (size_t)row0 * Kdim;
  const bf16* Bg = Wb + (size_t)(nt * BN) * Kdim;

  // staging geometry: per tile, A = 256 rows x 4 slots x 16B (16KB), B same.
  // thread covers chunks c = i*512+tid, i=0,1 -> A, i=2,3 -> B (same offsets).
  // LDS dest linear (c*16); global source pre-swizzled: slot ^ ((row>>1)&3).
  uint32_t srcO[2];
  {
    int rlo = tid >> 2, spos = tid & 3;
    #pragma unroll
    for (int i = 0; i < 2; ++i) {
      int row = i * 128 + rlo;
      srcO[i] = (uint32_t)(row * Kdim + ((spos ^ ((row >> 1) & 3)) << 3));
    }
  }
  const uint32_t dstBase = (uint32_t)(wid * 1024);  // bytes, wave-uniform

  // ds_read byte offsets (within ring slot); kslot = lane>>4, row stride 64B
  uint32_t byteA[8], byteB[4];
  {
    int kslot = lane >> 4;
    #pragma unroll
    for (int m = 0; m < 8; ++m) {
      int row = wr * 128 + m * 16 + (lane & 15);
      byteA[m] = (uint32_t)(row * 64 + ((kslot ^ ((row >> 1) & 3)) << 4));
    }
    #pragma unroll
    for (int n = 0; n < 4; ++n) {
      int row = wc * 64 + n * 16 + (lane & 15);
      byteB[n] = (uint32_t)(16384 + row * 64 + ((kslot ^ ((row >> 1) & 3)) << 4));
    }
  }

  f32x4 acc[8][4];
  #pragma unroll
  for (int m = 0; m < 8; ++m)
    #pragma unroll
    for (int n = 0; n < 4; ++n)
      acc[m][n] = (f32x4){0.f, 0.f, 0.f, 0.f};

  // prologue: stage tiles 0,1,2 into ring slots 0,1,2 (12 loads/thread)
  #pragma unroll
  for (int kt = 0; kt < 3; ++kt) {
    char* ring = lds + kt * 32768;
    #pragma unroll
    for (int i = 0; i < 2; ++i)
      gload_lds16(Ag + srcO[i] + kt * BK2, ring + i * 8192 + dstBase);
    #pragma unroll
    for (int i = 0; i < 2; ++i)
      gload_lds16(Bg + srcO[i] + kt * BK2, ring + 16384 + i * 8192 + dstBase);
  }
  asm volatile("s_waitcnt vmcnt(8)" ::: "memory");  // tile 0 landed (1,2 in flight)
  __builtin_amdgcn_s_barrier();
  __builtin_amdgcn_sched_barrier(0);

  #pragma unroll
  for (int t = 0; t < NT; ++t) {
    if (t + 3 < NT) {  // stage tile t+3 into ring slot (t+3)&3 (reuses t-1's slot)
      char* ring = lds + ((t + 3) & 3) * 32768;
      #pragma unroll
      for (int i = 0; i < 2; ++i)
        gload_lds16(Ag + srcO[i] + (t + 3) * BK2, ring + i * 8192 + dstBase);
      #pragma unroll
      for (int i = 0; i < 2; ++i)
        gload_lds16(Bg + srcO[i] + (t + 3) * BK2, ring + 16384 + i * 8192 + dstBase);
    }
    const char* Ab = lds + (t & 3) * 32768;
    bf16x8 af[8], bfrag[4];
    #pragma unroll
    for (int m = 0; m < 8; ++m) af[m] = *(const bf16x8*)(Ab + byteA[m]);
    #pragma unroll
    for (int n = 0; n < 4; ++n) bfrag[n] = *(const bf16x8*)(Ab + byteB[n]);
    __builtin_amdgcn_s_setprio(1);
    #pragma unroll
    for (int m = 0; m < 8; ++m)
      #pragma unroll
      for (int n = 0; n < 4; ++n)
        acc[m][n] = __builtin_amdgcn_mfma_f32_16x16x32_bf16(af[m], bfrag[n], acc[m][n], 0, 0, 0);
    __builtin_amdgcn_s_setprio(0);
    // end-of-iter: ensure tile t+1 landed everywhere; keep newer tiles in flight
    if (t <= NT - 4) {
      asm volatile("s_waitcnt vmcnt(8)" ::: "memory");
    } else if (t == NT - 3) {
      asm volatile("s_waitcnt vmcnt(4)" ::: "memory");
    } else if (t == NT - 2) {
      asm volatile("s_waitcnt vmcnt(0)" ::: "memory");
    }
    if (t < NT - 1) {
      __builtin_amdgcn_s_barrier();
      __builtin_amdgcn_sched_barrier(0);
    }
  }

  __syncthreads();  // full drain before LDS reuse by epilogue

  // ---- epilogue: activation, repack via LDS, coalesced f16x8 stores ----
  const int gate = nt >> 1;                 // BN=256 divides each 512-col gate
  const int cb   = (nt & 1) * 256;
  f16* dst = (gate == 0) ? zbuf : ((gate == 1) ? fbuf : ogbuf);
  float bv[4];
  #pragma unroll
  for (int n = 0; n < 4; ++n)
    bv[n] = bias[gate * Hdim + cb + wc * 64 + n * 16 + (lane & 15)];

  // write phase: scatter f16 into swizzled 256x256 tile (row stride 512B)
  #pragma unroll
  for (int m = 0; m < 8; ++m) {
    #pragma unroll
    for (int n = 0; n < 4; ++n) {
      int col = wc * 64 + n * 16 + (lane & 15);
      #pragma unroll
      for (int r = 0; r < 4; ++r) {
        int row = wr * 128 + m * 16 + (lane >> 4) * 4 + r;
        float y = acc[m][n][r] + bv[n];
        float v;
        if (gate == 0) {                       // tanh(y) = 1 - 2/(e^{2y}+1)
          float e = __expf(2.f * y);
          v = 1.f - 2.f / (e + 1.f);
        } else {                               // sigmoid
          v = 1.f / (1.f + __expf(-y));
        }
        uint32_t byte = (uint32_t)(row * 512 + col * 2) ^ ((uint32_t)(row & 7) << 4);
        *(f16*)(lds + byte) = (f16)v;
      }
    }
  }
  __syncthreads();
  // read phase: 16 rounds x 512 threads x 16B, contiguous global stores
  #pragma unroll
  for (int j = 0; j < 16; ++j) {
    int c = j * 512 + tid;
    int row = c >> 5, col8 = c & 31;        // 32 x 16B chunks per 512B row
    uint32_t byte = (uint32_t)(row * 512 + col8 * 16) ^ ((uint32_t)(row & 7) << 4);
    f16x8 v = *(const f16x8*)(lds + byte);
    *(f16x8*)&dst[(size_t)(row0 + row) * Hdim + cb + col8 * 8] = v;
  }
}

// ---------- scan pass A: per-chunk composite (P = prod(1-f), Q = local scan) ----------
__global__ void __launch_bounds__(256) scanA_kernel(const f16x4* __restrict__ z4,
                                                    const f16x4* __restrict__ f4,
                                                    float* __restrict__ Pb,
                                                    float* __restrict__ Qb) {
  int u  = blockIdx.x * blockDim.x + threadIdx.x;  // 131072 = NCHUNK*B*128
  int hq = u & 127;
  int bc = u >> 7;
  int b  = bc & (Bdim - 1);
  int c  = bc >> 4;
  size_t base = ((size_t)(b * Sdim + c * CLEN)) * 128 + hq;  // in quads
  float P[4] = {1.f, 1.f, 1.f, 1.f}, Q[4] = {0.f, 0.f, 0.f, 0.f};
  #pragma unroll 4
  for (int s = 0; s < CLEN; ++s) {
    f16x4 fv = f4[base], zv = z4[base];
    #pragma unroll
    for (int j = 0; j < 4; ++j) {
      float f = (float)fv[j];
      Q[j] += f * ((float)zv[j] - Q[j]);
      P[j] *= (1.f - f);
    }
    base += 128;
  }
  int outi = ((c * Bdim + b) << 9) + hq * 4;
  *(float4*)&Pb[outi] = make_float4(P[0], P[1], P[2], P[3]);
  *(float4*)&Qb[outi] = make_float4(Q[0], Q[1], Q[2], Q[3]);
}

// ---------- scan pass B: scan chunk composites -> h_in per chunk + c_last ----------
__global__ void __launch_bounds__(256) scanB_kernel(const float* __restrict__ Pb,
                                                    const float* __restrict__ Qb,
                                                    float* __restrict__ hin,
                                                    float* __restrict__ c_last) {
  int t = blockIdx.x * blockDim.x + threadIdx.x;  // 8192 = B*H
  int h = t & (Hdim - 1), b = t >> 9;
  float hs = 0.f;
  #pragma unroll 8
  for (int c = 0; c < NCHUNK; ++c) {
    hin[c * (Bdim * Hdim) + t] = hs;
    int u = ((c * Bdim + b) << 9) + h;
    hs = Pb[u] * hs + Qb[u];
  }
  c_last[t] = hs;
}

// ---------- scan pass C: rerun chunk with correct h_in, fuse out = og * h ----------
__global__ void __launch_bounds__(256) scanC_kernel(const f16x4* __restrict__ z4,
                                                    const f16x4* __restrict__ f4,
                                                    const f16x4* __restrict__ og4,
                                                    const float* __restrict__ hin,
                                                    float4* __restrict__ out4) {
  int u  = blockIdx.x * blockDim.x + threadIdx.x;
  int hq = u & 127;
  int bc = u >> 7;
  int b  = bc & (Bdim - 1);
  int c  = bc >> 4;
  float4 hv = *(const float4*)&hin[c * (Bdim * Hdim) + b * Hdim + hq * 4];
  float h[4] = {hv.x, hv.y, hv.z, hv.w};
  size_t base = ((size_t)(b * Sdim + c * CLEN)) * 128 + hq;
  #pragma unroll 4
  for (int s = 0; s < CLEN; ++s) {
    f16x4 fv = f4[base], zv = z4[base], ov = og4[base];
    float4 o;
    #pragma unroll
    for (int j = 0; j < 4; ++j) {
      h[j] += (float)fv[j] * ((float)zv[j] - h[j]);
    }
    o.x = (float)ov[0] * h[0]; o.y = (float)ov[1] * h[1];
    o.z = (float)ov[2] * h[2]; o.w = (float)ov[3] * h[3];
    out4[base] = o;
    base += 128;
  }
}

extern "C" void kernel_launch(void* const* d_in, const int* in_sizes, int n_in,
                              void* d_out, int out_size, void* d_ws, size_t ws_size,
                              hipStream_t stream) {
  const float* inp  = (const float*)d_in[0];
  const float* W    = (const float*)d_in[1];
  const float* bias = (const float*)d_in[2];
  float* out = (float*)d_out;

  char* ws = (char*)d_ws;
  // workspace layout (bytes), total ~276 MB
  bf16* Abf = (bf16*)(ws);                   //  67,108,864
  bf16* Wbf = (bf16*)(ws + 67108864);        //   1,572,864
  f16*  zh  = (f16*) (ws + 68681728);        //  67,108,864
  f16*  fh  = (f16*) (ws + 135790592);       //  67,108,864
  f16*  ogh = (f16*) (ws + 202899456);       //  67,108,864
  float* Pb = (float*)(ws + 270008320);      //   2,097,152
  float* Qb = (float*)(ws + 272105472);      //   2,097,152
  float* hin= (float*)(ws + 274202624);      //   2,097,152

  // 1) convert inp and W to bf16
  {
    int n4 = (Mdim * Kdim) / 4;  // 8,388,608
    cvt_kernel<<<n4 / 256, 256, 0, stream>>>((const float4*)inp, (bf16x4*)Abf, n4);
  }
  {
    int n4 = (N3 * Kdim) / 4;    // 196,608
    cvt_kernel<<<n4 / 256, 256, 0, stream>>>((const float4*)W, (bf16x4*)Wbf, n4);
  }
  // 2) GEMM + bias + activations -> fp16 gates
  gemm_act_kernel<<<(Mdim / BM) * (N3 / BN), 512, 0, stream>>>(Abf, Wbf, bias,
                                                               zh, fh, ogh);
  // 3) chunked linear-recurrence scan
  scanA_kernel<<<(NCHUNK * Bdim * 128) / 256, 256, 0, stream>>>(
      (const f16x4*)zh, (const f16x4*)fh, Pb, Qb);
  scanB_kernel<<<(Bdim * Hdim) / 256, 256, 0, stream>>>(Pb, Qb, hin,
                                                        out + (size_t)Mdim * Hdim);
  scanC_kernel<<<(NCHUNK * Bdim * 128) / 256, 256, 0, stream>>>(
      (const f16x4*)zh, (const f16x4*)fh, (const f16x4*)ogh, hin, (float4*)out);
}

// Round 5
// 310.812 us; speedup vs baseline: 1.0059x; 1.0059x over previous
//
#include <hip/hip_runtime.h>
#include <stdint.h>

#define Bdim 16
#define Sdim 4096
#define Hdim 512
#define Mdim (Bdim*Sdim)      // 65536
#define N3   (3*Hdim)         // 1536
#define Kdim 512
#define NCHUNK 64
#define CLEN  (Sdim/NCHUNK)   // 64

typedef __bf16 bf16;
typedef __bf16 bf16x4 __attribute__((ext_vector_type(4)));
typedef __bf16 bf16x8 __attribute__((ext_vector_type(8)));
typedef float  f32x4  __attribute__((ext_vector_type(4)));
typedef _Float16 f16;
typedef _Float16 f16x4 __attribute__((ext_vector_type(4)));
typedef _Float16 f16x8 __attribute__((ext_vector_type(8)));

__device__ __forceinline__ void gload_lds16(const void* g, void* l) {
  __builtin_amdgcn_global_load_lds(
      (const __attribute__((address_space(1))) uint32_t*)g,
      (__attribute__((address_space(3))) uint32_t*)l, 16, 0, 0);
}

// ---------- fp32 -> bf16 convert (vectorized) ----------
__global__ void __launch_bounds__(256) cvt_kernel(const float4* __restrict__ in,
                                                  bf16x4* __restrict__ out, int n4) {
  int i = blockIdx.x * blockDim.x + threadIdx.x;
  if (i >= n4) return;
  float4 v = in[i];
  bf16x4 o;
  o.x = (bf16)v.x; o.y = (bf16)v.y; o.z = (bf16)v.z; o.w = (bf16)v.w;
  out[i] = o;
}

// ---------- bf16 MFMA GEMM, 256x256 tile, ring pipeline, ds_read-FIRST order ----------
// A: (M,K) bf16 row-major; Wb: (N,K) bf16 row-major. C = A*Wb^T.
// BK=32, 4-slot LDS ring (4 x 32KB), prefetch distance 3. Iteration order:
// ds_read(t) -> issue stage(t+3) -> MFMA(t) -> vmcnt(8) -> s_barrier.
// Any compiler-inserted conservative DMA drain before ds_read(t) now waits on
// loads issued >=1 iteration ago (covered by MFMA+barrier), not fresh ones.
#define BM 256
#define BN 256
#define BK2 32
#define NT (Kdim/BK2)   // 16

__global__ void __launch_bounds__(512, 2) gemm_act_kernel(
    const bf16* __restrict__ A, const bf16* __restrict__ Wb,
    const float* __restrict__ bias,
    f16* __restrict__ zbuf, f16* __restrict__ fbuf, f16* __restrict__ ogbuf) {
  __shared__ char lds[131072];  // ring slot r at r*32768: A 16KB then B 16KB
  const int tid  = threadIdx.x;
  const int wid  = tid >> 6;
  const int lane = tid & 63;
  const int wr = wid >> 2, wc = wid & 3;   // 2(M) x 4(N) wave grid; wave tile 128x64
  // XCD-chunked bijective swizzle: 1536 blocks = 8 XCDs x 192
  const int bid = blockIdx.x;
  const int wg  = (bid & 7) * 192 + (bid >> 3);
  const int mt = wg / (N3 / BN);
  const int nt = wg % (N3 / BN);           // 6 N-tiles, inner -> A reuse per XCD
  const int row0 = mt * BM;

  const bf16* Ag = A  + (size_t)row0 * Kdim;
  const bf16* Bg = Wb + (size_t)(nt * BN) * Kdim;

  // staging geometry: per tile, A = 256 rows x 4 slots x 16B (16KB), B same.
  // LDS dest linear; global source pre-swizzled: slot ^ ((row>>1)&3).
  uint32_t srcO[2];
  {
    int rlo = tid >> 2, spos = tid & 3;
    #pragma unroll
    for (int i = 0; i < 2; ++i) {
      int row = i * 128 + rlo;
      srcO[i] = (uint32_t)(row * Kdim + ((spos ^ ((row >> 1) & 3)) << 3));
    }
  }
  const uint32_t dstBase = (uint32_t)(wid * 1024);  // bytes, wave-uniform

  // ds_read byte offsets (within ring slot); kslot = lane>>4, row stride 64B
  uint32_t byteA[8], byteB[4];
  {
    int kslot = lane >> 4;
    #pragma unroll
    for (int m = 0; m < 8; ++m) {
      int row = wr * 128 + m * 16 + (lane & 15);
      byteA[m] = (uint32_t)(row * 64 + ((kslot ^ ((row >> 1) & 3)) << 4));
    }
    #pragma unroll
    for (int n = 0; n < 4; ++n) {
      int row = wc * 64 + n * 16 + (lane & 15);
      byteB[n] = (uint32_t)(16384 + row * 64 + ((kslot ^ ((row >> 1) & 3)) << 4));
    }
  }

  f32x4 acc[8][4];
  #pragma unroll
  for (int m = 0; m < 8; ++m)
    #pragma unroll
    for (int n = 0; n < 4; ++n)
      acc[m][n] = (f32x4){0.f, 0.f, 0.f, 0.f};

  // prologue: stage tiles 0,1,2 into ring slots 0,1,2 (12 loads/thread)
  #pragma unroll
  for (int kt = 0; kt < 3; ++kt) {
    char* ring = lds + kt * 32768;
    #pragma unroll
    for (int i = 0; i < 2; ++i)
      gload_lds16(Ag + srcO[i] + kt * BK2, ring + i * 8192 + dstBase);
    #pragma unroll
    for (int i = 0; i < 2; ++i)
      gload_lds16(Bg + srcO[i] + kt * BK2, ring + 16384 + i * 8192 + dstBase);
  }
  asm volatile("s_waitcnt vmcnt(8)" ::: "memory");  // tile 0 landed (1,2 in flight)
  __builtin_amdgcn_s_barrier();
  __builtin_amdgcn_sched_barrier(0);

  #pragma unroll
  for (int t = 0; t < NT; ++t) {
    // ---- phase 1: fragment loads of tile t (compiler drain, if any, lands
    //      here and waits only on loads issued in earlier iterations) ----
    const char* Ab = lds + (t & 3) * 32768;
    bf16x8 af[8], bfrag[4];
    #pragma unroll
    for (int m = 0; m < 8; ++m) af[m] = *(const bf16x8*)(Ab + byteA[m]);
    #pragma unroll
    for (int n = 0; n < 4; ++n) bfrag[n] = *(const bf16x8*)(Ab + byteB[n]);
    __builtin_amdgcn_sched_barrier(0);  // pin: reads before stage-issue
    // ---- phase 2: issue stage of tile t+3 into ring slot (t+3)&3 ----
    if (t + 3 < NT) {
      char* ring = lds + ((t + 3) & 3) * 32768;
      #pragma unroll
      for (int i = 0; i < 2; ++i)
        gload_lds16(Ag + srcO[i] + (t + 3) * BK2, ring + i * 8192 + dstBase);
      #pragma unroll
      for (int i = 0; i < 2; ++i)
        gload_lds16(Bg + srcO[i] + (t + 3) * BK2, ring + 16384 + i * 8192 + dstBase);
    }
    // ---- phase 3: MFMA (shadows the in-flight stage) ----
    __builtin_amdgcn_s_setprio(1);
    #pragma unroll
    for (int m = 0; m < 8; ++m)
      #pragma unroll
      for (int n = 0; n < 4; ++n)
        acc[m][n] = __builtin_amdgcn_mfma_f32_16x16x32_bf16(af[m], bfrag[n], acc[m][n], 0, 0, 0);
    __builtin_amdgcn_s_setprio(0);
    // ---- phase 4: counted wait (tile t+1 landed; t+2,t+3 stay in flight) ----
    if (t <= NT - 4) {
      asm volatile("s_waitcnt vmcnt(8)" ::: "memory");
    } else if (t == NT - 3) {
      asm volatile("s_waitcnt vmcnt(4)" ::: "memory");
    } else if (t == NT - 2) {
      asm volatile("s_waitcnt vmcnt(0)" ::: "memory");
    }
    if (t < NT - 1) {
      __builtin_amdgcn_s_barrier();
      __builtin_amdgcn_sched_barrier(0);
    }
  }

  __syncthreads();  // full drain before LDS reuse by epilogue

  // ---- epilogue: activation, repack via LDS, coalesced f16x8 stores ----
  const int gate = nt >> 1;                 // BN=256 divides each 512-col gate
  const int cb   = (nt & 1) * 256;
  f16* dst = (gate == 0) ? zbuf : ((gate == 1) ? fbuf : ogbuf);
  float bv[4];
  #pragma unroll
  for (int n = 0; n < 4; ++n)
    bv[n] = bias[gate * Hdim + cb + wc * 64 + n * 16 + (lane & 15)];

  // write phase: scatter f16 into swizzled 256x256 tile (row stride 512B)
  #pragma unroll
  for (int m = 0; m < 8; ++m) {
    #pragma unroll
    for (int n = 0; n < 4; ++n) {
      int col = wc * 64 + n * 16 + (lane & 15);
      #pragma unroll
      for (int r = 0; r < 4; ++r) {
        int row = wr * 128 + m * 16 + (lane >> 4) * 4 + r;
        float y = acc[m][n][r] + bv[n];
        float v;
        if (gate == 0) {                       // tanh(y) = 1 - 2/(e^{2y}+1)
          float e = __expf(2.f * y);
          v = 1.f - 2.f / (e + 1.f);
        } else {                               // sigmoid
          v = 1.f / (1.f + __expf(-y));
        }
        uint32_t byte = (uint32_t)(row * 512 + col * 2) ^ ((uint32_t)(row & 7) << 4);
        *(f16*)(lds + byte) = (f16)v;
      }
    }
  }
  __syncthreads();
  // read phase: 16 rounds x 512 threads x 16B, contiguous global stores
  #pragma unroll
  for (int j = 0; j < 16; ++j) {
    int c = j * 512 + tid;
    int row = c >> 5, col8 = c & 31;        // 32 x 16B chunks per 512B row
    uint32_t byte = (uint32_t)(row * 512 + col8 * 16) ^ ((uint32_t)(row & 7) << 4);
    f16x8 v = *(const f16x8*)(lds + byte);
    *(f16x8*)&dst[(size_t)(row0 + row) * Hdim + cb + col8 * 8] = v;
  }
}

// ---------- scan pass A: per-chunk composite (P = prod(1-f), Q = local scan) ----------
__global__ void __launch_bounds__(256) scanA_kernel(const f16x4* __restrict__ z4,
                                                    const f16x4* __restrict__ f4,
                                                    float* __restrict__ Pb,
                                                    float* __restrict__ Qb) {
  int u  = blockIdx.x * blockDim.x + threadIdx.x;  // 131072 = NCHUNK*B*128
  int hq = u & 127;
  int bc = u >> 7;
  int b  = bc & (Bdim - 1);
  int c  = bc >> 4;
  size_t base = ((size_t)(b * Sdim + c * CLEN)) * 128 + hq;  // in quads
  float P[4] = {1.f, 1.f, 1.f, 1.f}, Q[4] = {0.f, 0.f, 0.f, 0.f};
  #pragma unroll 4
  for (int s = 0; s < CLEN; ++s) {
    f16x4 fv = f4[base], zv = z4[base];
    #pragma unroll
    for (int j = 0; j < 4; ++j) {
      float f = (float)fv[j];
      Q[j] += f * ((float)zv[j] - Q[j]);
      P[j] *= (1.f - f);
    }
    base += 128;
  }
  int outi = ((c * Bdim + b) << 9) + hq * 4;
  *(float4*)&Pb[outi] = make_float4(P[0], P[1], P[2], P[3]);
  *(float4*)&Qb[outi] = make_float4(Q[0], Q[1], Q[2], Q[3]);
}

// ---------- scan pass B: scan chunk composites -> h_in per chunk + c_last ----------
__global__ void __launch_bounds__(256) scanB_kernel(const float* __restrict__ Pb,
                                                    const float* __restrict__ Qb,
                                                    float* __restrict__ hin,
                                                    float* __restrict__ c_last) {
  int t = blockIdx.x * blockDim.x + threadIdx.x;  // 8192 = B*H
  int h = t & (Hdim - 1), b = t >> 9;
  float hs = 0.f;
  #pragma unroll 8
  for (int c = 0; c < NCHUNK; ++c) {
    hin[c * (Bdim * Hdim) + t] = hs;
    int u = ((c * Bdim + b) << 9) + h;
    hs = Pb[u] * hs + Qb[u];
  }
  c_last[t] = hs;
}

// ---------- scan pass C: rerun chunk with correct h_in, fuse out = og * h ----------
__global__ void __launch_bounds__(256) scanC_kernel(const f16x4* __restrict__ z4,
                                                    const f16x4* __restrict__ f4,
                                                    const f16x4* __restrict__ og4,
                                                    const float* __restrict__ hin,
                                                    float4* __restrict__ out4) {
  int u  = blockIdx.x * blockDim.x + threadIdx.x;
  int hq = u & 127;
  int bc = u >> 7;
  int b  = bc & (Bdim - 1);
  int c  = bc >> 4;
  float4 hv = *(const float4*)&hin[c * (Bdim * Hdim) + b * Hdim + hq * 4];
  float h[4] = {hv.x, hv.y, hv.z, hv.w};
  size_t base = ((size_t)(b * Sdim + c * CLEN)) * 128 + hq;
  #pragma unroll 4
  for (int s = 0; s < CLEN; ++s) {
    f16x4 fv = f4[base], zv = z4[base], ov = og4[base];
    float4 o;
    #pragma unroll
    for (int j = 0; j < 4; ++j) {
      h[j] += (float)fv[j] * ((float)zv[j] - h[j]);
    }
    o.x = (float)ov[0] * h[0]; o.y = (float)ov[1] * h[1];
    o.z = (float)ov[2] * h[2]; o.w = (float)ov[3] * h[3];
    out4[base] = o;
    base += 128;
  }
}

extern "C" void kernel_launch(void* const* d_in, const int* in_sizes, int n_in,
                              void* d_out, int out_size, void* d_ws, size_t ws_size,
                              hipStream_t stream) {
  const float* inp  = (const float*)d_in[0];
  const float* W    = (const float*)d_in[1];
  const float* bias = (const float*)d_in[2];
  float* out = (float*)d_out;

  char* ws = (char*)d_ws;
  // workspace layout (bytes), total ~276 MB
  bf16* Abf = (bf16*)(ws);                   //  67,108,864
  bf16* Wbf = (bf16*)(ws + 67108864);        //   1,572,864
  f16*  zh  = (f16*) (ws + 68681728);        //  67,108,864
  f16*  fh  = (f16*) (ws + 135790592);       //  67,108,864
  f16*  ogh = (f16*) (ws + 202899456);       //  67,108,864
  float* Pb = (float*)(ws + 270008320);      //   2,097,152
  float* Qb = (float*)(ws + 272105472);      //   2,097,152
  float* hin= (float*)(ws + 274202624);      //   2,097,152

  // 1) convert inp and W to bf16
  {
    int n4 = (Mdim * Kdim) / 4;  // 8,388,608
    cvt_kernel<<<n4 / 256, 256, 0, stream>>>((const float4*)inp, (bf16x4*)Abf, n4);
  }
  {
    int n4 = (N3 * Kdim) / 4;    // 196,608
    cvt_kernel<<<n4 / 256, 256, 0, stream>>>((const float4*)W, (bf16x4*)Wbf, n4);
  }
  // 2) GEMM + bias + activations -> fp16 gates
  gemm_act_kernel<<<(Mdim / BM) * (N3 / BN), 512, 0, stream>>>(Abf, Wbf, bias,
                                                               zh, fh, ogh);
  // 3) chunked linear-recurrence scan
  scanA_kernel<<<(NCHUNK * Bdim * 128) / 256, 256, 0, stream>>>(
      (const f16x4*)zh, (const f16x4*)fh, Pb, Qb);
  scanB_kernel<<<(Bdim * Hdim) / 256, 256, 0, stream>>>(Pb, Qb, hin,
                                                        out + (size_t)Mdim * Hdim);
  scanC_kernel<<<(NCHUNK * Bdim * 128) / 256, 256, 0, stream>>>(
      (const f16x4*)zh, (const f16x4*)fh, (const f16x4*)ogh, hin, (float4*)out);
}

// Round 6
// 308.357 us; speedup vs baseline: 1.0139x; 1.0080x over previous
//
#include <hip/hip_runtime.h>
#include <stdint.h>

#define Bdim 16
#define Sdim 4096
#define Hdim 512
#define Mdim (Bdim*Sdim)      // 65536
#define N3   (3*Hdim)         // 1536
#define Kdim 512
#define NCHUNK 64
#define CLEN  (Sdim/NCHUNK)   // 64

typedef __bf16 bf16;
typedef __bf16 bf16x4 __attribute__((ext_vector_type(4)));
typedef __bf16 bf16x8 __attribute__((ext_vector_type(8)));
typedef float  f32x4  __attribute__((ext_vector_type(4)));
typedef _Float16 f16;
typedef _Float16 f16x4 __attribute__((ext_vector_type(4)));
typedef _Float16 f16x8 __attribute__((ext_vector_type(8)));

__device__ __forceinline__ void gload_lds16(const void* g, void* l) {
  __builtin_amdgcn_global_load_lds(
      (const __attribute__((address_space(1))) uint32_t*)g,
      (__attribute__((address_space(3))) uint32_t*)l, 16, 0, 0);
}

// ---------- fp32 -> bf16 convert (vectorized) ----------
__global__ void __launch_bounds__(256) cvt_kernel(const float4* __restrict__ in,
                                                  bf16x4* __restrict__ out, int n4) {
  int i = blockIdx.x * blockDim.x + threadIdx.x;
  if (i >= n4) return;
  float4 v = in[i];
  bf16x4 o;
  o.x = (bf16)v.x; o.y = (bf16)v.y; o.z = (bf16)v.z; o.w = (bf16)v.w;
  out[i] = o;
}

// ================= 8-phase 256x256 MFMA GEMM (m201 template port) ==========
// A: (M,K) bf16 row-major; Wb: (N,K) bf16 row-major. C = A*Wb^T, fused act.
// BK=64 per K-tile, 8 K-tiles. LDS: 2 buffers x (A 32KB + B 32KB) = 128KB.
// Half-tiles (16KB, 128 rows x 64k): stream H = 4t+s, s: 0=A rows0-127,
// 1=B rows0-127, 2=A rows128-255, 3=B rows128-255; half H staged at phase H-6
// (6-phase lead), one half (2 gload_lds/thread) per phase.
// Phase q of tile t: reads quadrant regs; stage; bar; lgkm0; 16 MFMA; [vmcnt@p3]; bar.
// Slot swizzle: 16B-slot s' = s ^ (row&7), applied at stage source AND ds_read.
#define BM 256
#define BN 256
#define BKT 64
#define NKT (Kdim/BKT)   // 8

__device__ __forceinline__ bf16x8 lds_ld(const char* p) { return *(const bf16x8*)p; }

__device__ __forceinline__ void read_af(bf16x8 (&d)[4][2], const char* Lb, uint32_t base,
                                        uint32_t swk0, uint32_t swk1, int mh) {
  #pragma unroll
  for (int i = 0; i < 4; ++i) {
    d[i][0] = lds_ld(Lb + base + mh * 8192 + i * 2048 + swk0);
    d[i][1] = lds_ld(Lb + base + mh * 8192 + i * 2048 + swk1);
  }
}
__device__ __forceinline__ void read_bf(bf16x8 (&d)[2][2], const char* Lb, uint32_t base,
                                        uint32_t swk0, uint32_t swk1, int nh) {
  #pragma unroll
  for (int j = 0; j < 2; ++j) {
    d[j][0] = lds_ld(Lb + base + nh * 4096 + j * 2048 + swk0);
    d[j][1] = lds_ld(Lb + base + nh * 4096 + j * 2048 + swk1);
  }
}
__device__ __forceinline__ void chunk16(f32x4 (&acc)[8][4], const bf16x8 (&a)[4][2],
                                        const bf16x8 (&b)[2][2], int mb, int nb) {
  __builtin_amdgcn_s_setprio(1);
  #pragma unroll
  for (int i = 0; i < 4; ++i)
    #pragma unroll
    for (int j = 0; j < 2; ++j)
      #pragma unroll
      for (int kk = 0; kk < 2; ++kk)
        acc[mb + i][nb + j] =
            __builtin_amdgcn_mfma_f32_16x16x32_bf16(a[i][kk], b[j][kk], acc[mb + i][nb + j], 0, 0, 0);
  __builtin_amdgcn_s_setprio(0);
}

template <int H>
__device__ __forceinline__ void stage_half(const bf16* Ag, const bf16* Bg, char* lds,
                                           uint32_t so0, uint32_t wbase) {
  if constexpr (H <= 4 * NKT - 1) {
    constexpr int th = H >> 2, ss = H & 3;
    constexpr uint32_t goff = (uint32_t)((ss >> 1) * 128 * Kdim + th * BKT);
    constexpr uint32_t lbase = (uint32_t)((th & 1) * 65536 + (ss & 1) * 32768 + (ss >> 1) * 16384);
    const bf16* gp = (ss & 1) ? Bg : Ag;
    gload_lds16(gp + goff + so0,         lds + lbase + wbase);
    gload_lds16(gp + goff + so0 + 32768, lds + lbase + 8192 + wbase);
  }
}

#define BAR()   __builtin_amdgcn_s_barrier()
#define LGKM0() do { asm volatile("s_waitcnt lgkmcnt(0)" ::: "memory"); \
                     __builtin_amdgcn_sched_barrier(0); } while (0)

template <int T>
__device__ __forceinline__ void ktile(char* lds, f32x4 (&acc)[8][4],
    bf16x8 (&af0)[4][2], bf16x8 (&af1)[4][2], bf16x8 (&bf0)[2][2], bf16x8 (&bf1)[2][2],
    const bf16* Ag, const bf16* Bg, uint32_t so0, uint32_t wbase,
    uint32_t aBase, uint32_t bBase, uint32_t swk0, uint32_t swk1) {
  const char* Lb = lds + (T & 1) * 65536;
  // ---- p0: quadrant (m-half0, n-half0) ----
  read_af(af0, Lb, aBase, swk0, swk1, 0);
  read_bf(bf0, Lb, bBase, swk0, swk1, 0);
  stage_half<4 * T + 6>(Ag, Bg, lds, so0, wbase);
  BAR(); LGKM0();
  chunk16(acc, af0, bf0, 0, 0);
  BAR();
  // ---- p1: (m-half1, n-half0) ----
  read_af(af1, Lb, aBase, swk0, swk1, 1);
  stage_half<4 * T + 7>(Ag, Bg, lds, so0, wbase);
  BAR(); LGKM0();
  chunk16(acc, af1, bf0, 4, 0);
  BAR();
  // ---- p2: (m-half1, n-half1) ----
  read_bf(bf1, Lb, bBase, swk0, swk1, 1);
  stage_half<4 * T + 8>(Ag, Bg, lds, so0, wbase);
  BAR(); LGKM0();
  chunk16(acc, af1, bf1, 4, 2);
  BAR();
  // ---- p3: (m-half0, n-half1) ----
  stage_half<4 * T + 9>(Ag, Bg, lds, so0, wbase);
  BAR(); LGKM0();
  chunk16(acc, af0, bf1, 0, 2);
  if constexpr (T <= NKT - 3) {
    asm volatile("s_waitcnt vmcnt(4)" ::: "memory");  // tile T+1 fully landed
  } else if constexpr (T == NKT - 2) {
    asm volatile("s_waitcnt vmcnt(0)" ::: "memory");  // last tile landed
  }
  BAR();
}

__global__ void __launch_bounds__(512, 2) gemm_act_kernel(
    const bf16* __restrict__ A, const bf16* __restrict__ Wb,
    const float* __restrict__ bias,
    f16* __restrict__ zbuf, f16* __restrict__ fbuf, f16* __restrict__ ogbuf) {
  __shared__ char lds[131072];
  const int tid  = threadIdx.x;
  const int wid  = tid >> 6;
  const int lane = tid & 63;
  const int wr = wid >> 2, wc = wid & 3;   // 2(M) x 4(N) waves; wave tile 128x64
  // XCD-chunked bijective swizzle: 1536 blocks = 8 XCDs x 192
  const int bid = blockIdx.x;
  const int wg  = (bid & 7) * 192 + (bid >> 3);
  const int mt = wg / (N3 / BN);
  const int nt = wg % (N3 / BN);           // 6 N-tiles, inner -> A reuse per XCD
  const int row0 = mt * BM;

  const bf16* Ag = A  + (size_t)row0 * Kdim;
  const bf16* Bg = Wb + (size_t)(nt * BN) * Kdim;

  // staging addressing: thread covers rows r0 and r0+64 of a half, slot=tid&7
  const uint32_t r0   = tid >> 3;
  const uint32_t slot = tid & 7;
  const uint32_t so0  = r0 * Kdim + ((slot ^ (r0 & 7)) << 3);  // elements
  const uint32_t wbase = (uint32_t)(wid * 1024);               // bytes (LDS dest)
  // ds_read addressing (within 64KB buffer)
  const uint32_t kslot = lane >> 4;
  const uint32_t swk0 = ((kslot)     ^ (uint32_t)(lane & 7)) << 4;
  const uint32_t swk1 = ((4 + kslot) ^ (uint32_t)(lane & 7)) << 4;
  const uint32_t aBase = (uint32_t)((wr * 128 + (lane & 15)) * 128);
  const uint32_t bBase = (uint32_t)(32768 + (wc * 64 + (lane & 15)) * 128);

  f32x4 acc[8][4];
  #pragma unroll
  for (int m = 0; m < 8; ++m)
    #pragma unroll
    for (int n = 0; n < 4; ++n)
      acc[m][n] = (f32x4){0.f, 0.f, 0.f, 0.f};
  bf16x8 af0[4][2], af1[4][2], bf0[2][2], bf1[2][2];

  // prologue: stage halves 0..5 (tile0 complete + tile1 A0,B0)
  stage_half<0>(Ag, Bg, lds, so0, wbase);
  stage_half<1>(Ag, Bg, lds, so0, wbase);
  stage_half<2>(Ag, Bg, lds, so0, wbase);
  stage_half<3>(Ag, Bg, lds, so0, wbase);
  stage_half<4>(Ag, Bg, lds, so0, wbase);
  stage_half<5>(Ag, Bg, lds, so0, wbase);
  asm volatile("s_waitcnt vmcnt(4)" ::: "memory");  // tile 0 landed (halves 4,5 in flight)
  BAR();

  ktile<0>(lds, acc, af0, af1, bf0, bf1, Ag, Bg, so0, wbase, aBase, bBase, swk0, swk1);
  ktile<1>(lds, acc, af0, af1, bf0, bf1, Ag, Bg, so0, wbase, aBase, bBase, swk0, swk1);
  ktile<2>(lds, acc, af0, af1, bf0, bf1, Ag, Bg, so0, wbase, aBase, bBase, swk0, swk1);
  ktile<3>(lds, acc, af0, af1, bf0, bf1, Ag, Bg, so0, wbase, aBase, bBase, swk0, swk1);
  ktile<4>(lds, acc, af0, af1, bf0, bf1, Ag, Bg, so0, wbase, aBase, bBase, swk0, swk1);
  ktile<5>(lds, acc, af0, af1, bf0, bf1, Ag, Bg, so0, wbase, aBase, bBase, swk0, swk1);
  ktile<6>(lds, acc, af0, af1, bf0, bf1, Ag, Bg, so0, wbase, aBase, bBase, swk0, swk1);
  ktile<7>(lds, acc, af0, af1, bf0, bf1, Ag, Bg, so0, wbase, aBase, bBase, swk0, swk1);

  __syncthreads();  // full drain before LDS reuse by epilogue

  // ---- epilogue: activation, repack via LDS, coalesced f16x8 stores ----
  const int gate = nt >> 1;                 // BN=256 divides each 512-col gate
  const int cb   = (nt & 1) * 256;
  f16* dst = (gate == 0) ? zbuf : ((gate == 1) ? fbuf : ogbuf);
  float bv[4];
  #pragma unroll
  for (int n = 0; n < 4; ++n)
    bv[n] = bias[gate * Hdim + cb + wc * 64 + n * 16 + (lane & 15)];

  // write phase: scatter f16 into swizzled 256x256 tile (row stride 512B)
  #pragma unroll
  for (int m = 0; m < 8; ++m) {
    #pragma unroll
    for (int n = 0; n < 4; ++n) {
      int col = wc * 64 + n * 16 + (lane & 15);
      #pragma unroll
      for (int r = 0; r < 4; ++r) {
        int row = wr * 128 + m * 16 + (lane >> 4) * 4 + r;
        float y = acc[m][n][r] + bv[n];
        float v;
        if (gate == 0) {                       // tanh(y) = 1 - 2/(e^{2y}+1)
          float e = __expf(2.f * y);
          v = 1.f - 2.f / (e + 1.f);
        } else {                               // sigmoid
          v = 1.f / (1.f + __expf(-y));
        }
        uint32_t byte = (uint32_t)(row * 512 + col * 2) ^ ((uint32_t)(row & 7) << 4);
        *(f16*)(lds + byte) = (f16)v;
      }
    }
  }
  __syncthreads();
  // read phase: 16 rounds x 512 threads x 16B, contiguous global stores
  #pragma unroll
  for (int j = 0; j < 16; ++j) {
    int c = j * 512 + tid;
    int row = c >> 5, col8 = c & 31;        // 32 x 16B chunks per 512B row
    uint32_t byte = (uint32_t)(row * 512 + col8 * 16) ^ ((uint32_t)(row & 7) << 4);
    f16x8 v = *(const f16x8*)(lds + byte);
    *(f16x8*)&dst[(size_t)(row0 + row) * Hdim + cb + col8 * 8] = v;
  }
}

// ---------- scan pass A: per-chunk composite (P = prod(1-f), Q = local scan) ----------
__global__ void __launch_bounds__(256) scanA_kernel(const f16x4* __restrict__ z4,
                                                    const f16x4* __restrict__ f4,
                                                    float* __restrict__ Pb,
                                                    float* __restrict__ Qb) {
  int u  = blockIdx.x * blockDim.x + threadIdx.x;  // 131072 = NCHUNK*B*128
  int hq = u & 127;
  int bc = u >> 7;
  int b  = bc & (Bdim - 1);
  int c  = bc >> 4;
  size_t base = ((size_t)(b * Sdim + c * CLEN)) * 128 + hq;  // in quads
  float P[4] = {1.f, 1.f, 1.f, 1.f}, Q[4] = {0.f, 0.f, 0.f, 0.f};
  #pragma unroll 4
  for (int s = 0; s < CLEN; ++s) {
    f16x4 fv = f4[base], zv = z4[base];
    #pragma unroll
    for (int j = 0; j < 4; ++j) {
      float f = (float)fv[j];
      Q[j] += f * ((float)zv[j] - Q[j]);
      P[j] *= (1.f - f);
    }
    base += 128;
  }
  int outi = ((c * Bdim + b) << 9) + hq * 4;
  *(float4*)&Pb[outi] = make_float4(P[0], P[1], P[2], P[3]);
  *(float4*)&Qb[outi] = make_float4(Q[0], Q[1], Q[2], Q[3]);
}

// ---------- scan pass B: scan chunk composites -> h_in per chunk + c_last ----------
__global__ void __launch_bounds__(256) scanB_kernel(const float* __restrict__ Pb,
                                                    const float* __restrict__ Qb,
                                                    float* __restrict__ hin,
                                                    float* __restrict__ c_last) {
  int t = blockIdx.x * blockDim.x + threadIdx.x;  // 8192 = B*H
  int h = t & (Hdim - 1), b = t >> 9;
  float hs = 0.f;
  #pragma unroll 8
  for (int c = 0; c < NCHUNK; ++c) {
    hin[c * (Bdim * Hdim) + t] = hs;
    int u = ((c * Bdim + b) << 9) + h;
    hs = Pb[u] * hs + Qb[u];
  }
  c_last[t] = hs;
}

// ---------- scan pass C: rerun chunk with correct h_in, fuse out = og * h ----------
__global__ void __launch_bounds__(256) scanC_kernel(const f16x4* __restrict__ z4,
                                                    const f16x4* __restrict__ f4,
                                                    const f16x4* __restrict__ og4,
                                                    const float* __restrict__ hin,
                                                    float4* __restrict__ out4) {
  int u  = blockIdx.x * blockDim.x + threadIdx.x;
  int hq = u & 127;
  int bc = u >> 7;
  int b  = bc & (Bdim - 1);
  int c  = bc >> 4;
  float4 hv = *(const float4*)&hin[c * (Bdim * Hdim) + b * Hdim + hq * 4];
  float h[4] = {hv.x, hv.y, hv.z, hv.w};
  size_t base = ((size_t)(b * Sdim + c * CLEN)) * 128 + hq;
  #pragma unroll 4
  for (int s = 0; s < CLEN; ++s) {
    f16x4 fv = f4[base], zv = z4[base], ov = og4[base];
    float4 o;
    #pragma unroll
    for (int j = 0; j < 4; ++j) {
      h[j] += (float)fv[j] * ((float)zv[j] - h[j]);
    }
    o.x = (float)ov[0] * h[0]; o.y = (float)ov[1] * h[1];
    o.z = (float)ov[2] * h[2]; o.w = (float)ov[3] * h[3];
    out4[base] = o;
    base += 128;
  }
}

extern "C" void kernel_launch(void* const* d_in, const int* in_sizes, int n_in,
                              void* d_out, int out_size, void* d_ws, size_t ws_size,
                              hipStream_t stream) {
  const float* inp  = (const float*)d_in[0];
  const float* W    = (const float*)d_in[1];
  const float* bias = (const float*)d_in[2];
  float* out = (float*)d_out;

  char* ws = (char*)d_ws;
  // workspace layout (bytes), total ~276 MB
  bf16* Abf = (bf16*)(ws);                   //  67,108,864
  bf16* Wbf = (bf16*)(ws + 67108864);        //   1,572,864
  f16*  zh  = (f16*) (ws + 68681728);        //  67,108,864
  f16*  fh  = (f16*) (ws + 135790592);       //  67,108,864
  f16*  ogh = (f16*) (ws + 202899456);       //  67,108,864
  float* Pb = (float*)(ws + 270008320);      //   2,097,152
  float* Qb = (float*)(ws + 272105472);      //   2,097,152
  float* hin= (float*)(ws + 274202624);      //   2,097,152

  // 1) convert inp and W to bf16
  {
    int n4 = (Mdim * Kdim) / 4;  // 8,388,608
    cvt_kernel<<<n4 / 256, 256, 0, stream>>>((const float4*)inp, (bf16x4*)Abf, n4);
  }
  {
    int n4 = (N3 * Kdim) / 4;    // 196,608
    cvt_kernel<<<n4 / 256, 256, 0, stream>>>((const float4*)W, (bf16x4*)Wbf, n4);
  }
  // 2) GEMM + bias + activations -> fp16 gates
  gemm_act_kernel<<<(Mdim / BM) * (N3 / BN), 512, 0, stream>>>(Abf, Wbf, bias,
                                                               zh, fh, ogh);
  // 3) chunked linear-recurrence scan
  scanA_kernel<<<(NCHUNK * Bdim * 128) / 256, 256, 0, stream>>>(
      (const f16x4*)zh, (const f16x4*)fh, Pb, Qb);
  scanB_kernel<<<(Bdim * Hdim) / 256, 256, 0, stream>>>(Pb, Qb, hin,
                                                        out + (size_t)Mdim * Hdim);
  scanC_kernel<<<(NCHUNK * Bdim * 128) / 256, 256, 0, stream>>>(
      (const f16x4*)zh, (const f16x4*)fh, (const f16x4*)ogh, hin, (float4*)out);
}